// Round 11
// baseline (1265.779 us; speedup 1.0000x reference)
//
#include <hip/hip_runtime.h>
#include <hip/hip_bf16.h>

#define B_ 256
#define T_ 512
#define E_ 128
#define H_ 256

typedef __attribute__((ext_vector_type(8))) short short8;
typedef __attribute__((ext_vector_type(4))) float f32x4;
typedef unsigned short u16;

#define MFMA_BF16(a, b, c) __builtin_amdgcn_mfma_f32_16x16x32_bf16((a), (b), (c), 0, 0, 0)

__device__ __forceinline__ u16 f2bf(float f) {
    union { float f; unsigned int u; } v; v.f = f;
    unsigned int u = v.u;
    unsigned int r = (u + 0x7fffu + ((u >> 16) & 1u)) >> 16;  // RNE
    return (u16)r;
}
__device__ __forceinline__ float bflo(unsigned int u) {
    union { unsigned int u; float f; } v; v.u = u << 16; return v.f;
}
__device__ __forceinline__ float bfhi(unsigned int u) {
    union { unsigned int u; float f; } v; v.u = u & 0xffff0000u; return v.f;
}
__device__ __forceinline__ f32x4 up2(uint2 p) {
    f32x4 r; r[0] = bflo(p.x); r[1] = bfhi(p.x); r[2] = bflo(p.y); r[3] = bfhi(p.y); return r;
}
// hardware packed f32->bf16 (RNE), 1 instr per 2 values (guide T12 recipe)
__device__ __forceinline__ uint2 pk4(float a, float b, float c, float d) {
    uint2 o;
    asm("v_cvt_pk_bf16_f32 %0, %1, %2" : "=v"(o.x) : "v"(a), "v"(b));
    asm("v_cvt_pk_bf16_f32 %0, %1, %2" : "=v"(o.y) : "v"(c), "v"(d));
    return o;
}
__device__ __forceinline__ float rcp_f(float x) { return __builtin_amdgcn_rcpf(x); }
__device__ __forceinline__ float sigm(float x) { return rcp_f(1.f + __expf(-x)); }

// ---------------- fp32 -> bf16 weight conversion ----------------
__global__ void f32_to_bf16_kernel(const float* __restrict__ src, u16* __restrict__ dst, int n2) {
    int i = blockIdx.x * blockDim.x + threadIdx.x;
    if (i < n2) {
        float2 v = ((const float2*)src)[i];
        ushort2 o; o.x = f2bf(v.x); o.y = f2bf(v.y);
        ((ushort2*)dst)[i] = o;
    }
}

// ---------------- fused chunk kernel: xp producer (chunk c) + GRU consumer (chunk c-1) ----------
// R10 post-mortem (183us/dispatch, 1.43us/step = 3430cyc): per-CU LDS traffic was the floor —
// hv 128KB + bn 128KB per step ~ 3000cyc at 85B/cyc. R11: n-gate weight fragments load
// DIRECTLY from global (L2-hot, same row pattern as wr/wz) instead of via a 128KB LDS stage
// -> LDS traffic/step halves. wn stays DECLARED (producer A overlay + keeps LDS_Block_Size
// at 144KB so gru CUs stay exclusive). waves_per_eu(4,4) grants the full 128-VGPR budget
// (4 waves/SIMD is already forced by 1024thr x 1 block/CU).
//
// xp layout (bf16, packed as uint2 per lane): ring slot = (chunkparity)*2C + dir*C + lt, then
//   [slot][btile16][gtile48][lane64]; gates r,z (gt<32) have b_ih+b_hh folded; n-gate b_ih only.
// Ring has 4C+1 slots; ls=C-1 prefetch reads stale/pad data that is always discarded (benign).
// Blocks 0..31 = GRU (scheduled first), blocks 32..32+8C-1 = xp producers.
// No intra-launch data dependency: gru reads ring parity (c-1)&1, xp writes parity c&1.
#define XP_SLOT_U2 49152   // 16*48*64 uint2 per t-slot

__attribute__((amdgpu_flat_work_group_size(1024, 1024), amdgpu_waves_per_eu(4, 4)))
__global__ void fused_chunk_kernel(const int* __restrict__ x, const float* __restrict__ emb,
                                   const u16* __restrict__ wih, const u16* __restrict__ whh,
                                   const float* __restrict__ bih_f, const float* __restrict__ bhh_f,
                                   const float* __restrict__ bih_b, const float* __restrict__ bhh_b,
                                   const int* __restrict__ lengths,
                                   float* __restrict__ hstate,   // [dir][256][256] f32
                                   u16* __restrict__ xp,
                                   int C, int c, int nchunks) {
    // LDS: gru uses hfr only; wn reserves space (producer A overlay + CU-exclusivity pad)
    __shared__ u16 hfr[2][4096];    // 16KB h mirrors, fragment-linear
    __shared__ u16 wn[65536];       // 128KB: producer A-tile overlay; gru: exclusivity pad

    const int tid  = threadIdx.x;
    const int lane = tid & 63;
    const int nl   = lane & 15;
    const int quad = lane >> 4;
    const int wv   = tid >> 6;      // 0..15

    if (blockIdx.x < 32) {
        // ================= GRU consumer: chunk g = c-1 =================
        const int g = c - 1;
        if (g < 0) return;
        const int c0 = g * C;
        const int rg = g & 1;
        const int dir    = blockIdx.x >> 4;
        const int btile  = blockIdx.x & 15;
        const int b_base = btile << 4;

        __builtin_amdgcn_s_setprio(1);

        const u16*   whh_d = whh + (size_t)dir * (768 * 256);
        const float* bhh   = dir ? bhh_b : bhh_f;

        // weight fragment sets for this wave's 16 units: r (row wv*16+nl), z (+256), n (+512)
        // — all direct from global (L2-hot); compiler keeps resident within 128-VGPR budget
        // or re-streams, either is fine (per-XCD L2 share covers it).
        const u16* pwr = whh_d + (size_t)(wv * 16 + nl) * 256 + quad * 8;
        const u16* pwz = whh_d + (size_t)(256 + wv * 16 + nl) * 256 + quad * 8;
        const u16* pwn = whh_d + (size_t)(512 + wv * 16 + nl) * 256 + quad * 8;
        short8 wr[8], wz[8], wn8[8];
#pragma unroll
        for (int kt = 0; kt < 8; kt++) {
            wr[kt]  = *(const short8*)(pwr + kt * 32);
            wz[kt]  = *(const short8*)(pwz + kt * 32);
            wn8[kt] = *(const short8*)(pwn + kt * 32);
        }

        const float4 bnh = *(const float4*)(bhh + 512 + wv * 16 + quad * 4);
        const int len = lengths[b_base + nl];

        // h master copy (fp32): hreg[rr] = h[batch nl][unit wv*16 + quad*4 + rr]
        float hreg[4];
        const int u0   = wv * 16 + quad * 4;
        const int widx = ((u0 >> 3) * 16 + nl) * 8 + (u0 & 7);
        float* hs = hstate + ((size_t)(dir * 256 + b_base + nl)) * 256 + u0;
        if (c0 == 0) {
#pragma unroll
            for (int rr = 0; rr < 4; rr++) hreg[rr] = 0.f;
        } else {
            float4 h4 = *(const float4*)hs;
            hreg[0] = h4.x; hreg[1] = h4.y; hreg[2] = h4.z; hreg[3] = h4.w;
        }
        *(uint2*)&hfr[0][widx] = pk4(hreg[0], hreg[1], hreg[2], hreg[3]);

        // xp pointers: wave wv's tiles are gt = gate*16 + wv
        const uint2* pgr;
        const uint2* pgz;
        const uint2* pgn;
        {
            size_t base = (((size_t)(rg * 2 * C + dir * C) * 16 + btile) * 48) * 64 + lane;
            pgr = (const uint2*)xp + base + (0 * 16 + wv) * 64;
            pgz = (const uint2*)xp + base + (1 * 16 + wv) * 64;
            pgn = (const uint2*)xp + base + (2 * 16 + wv) * 64;
        }
        uint2 pfr = pgr[0], pfz = pgz[0], pfn = pgn[0];

        __syncthreads();

        for (int ls = 0; ls < C; ls++) {
            const int s = c0 + ls;
            const int t = dir ? (T_ - 1 - s) : s;
            const int cur = ls & 1, nxt = cur ^ 1;

            f32x4 accr = up2(pfr);
            f32x4 accz = up2(pfz);
            f32x4 xpn  = up2(pfn);
            f32x4 accn = (f32x4){bnh.x, bnh.y, bnh.z, bnh.w};

            // prefetch next local step (ls=C-1 lands in stale/pad region; discarded)
            pgr += XP_SLOT_U2; pgz += XP_SLOT_U2; pgn += XP_SLOT_U2;
            pfr = pgr[0]; pfz = pgz[0]; pfn = pgn[0];

#pragma unroll
            for (int kt = 0; kt < 8; kt++) {
                short8 hv = *(const short8*)&hfr[cur][(kt * 64 + lane) * 8];
                accr = MFMA_BF16(wr[kt],  hv, accr);
                accz = MFMA_BF16(wz[kt],  hv, accz);
                accn = MFMA_BF16(wn8[kt], hv, accn);
            }

            const bool upd = (t < len);
#pragma unroll
            for (int rr = 0; rr < 4; rr++) {
                float r = sigm(accr[rr]);
                float z = sigm(accz[rr]);
                float npre = xpn[rr] + r * accn[rr];
                float nn = 1.f - 2.f * rcp_f(1.f + __expf(2.f * npre));
                float hn = nn + z * (hreg[rr] - nn);
                if (upd) hreg[rr] = hn;
            }
            *(uint2*)&hfr[nxt][widx] = pk4(hreg[0], hreg[1], hreg[2], hreg[3]);
            __syncthreads();
        }

        // carry h out
        *(float4*)hs = (float4){hreg[0], hreg[1], hreg[2], hreg[3]};
    } else {
        // ================= xp producer: chunk c (1024 threads: 3 gtiles/wave) =========
        if (c >= nchunks) return;
        u16 (*A)[136] = (u16 (*)[136])wn;

        const int mb0 = (int)blockIdx.x - 32;
        const int per_dir = C * 4;
        const int dir = (mb0 >= per_dir) ? 1 : 0;
        const int mb  = mb0 - dir * per_dir;
        const int lt  = mb >> 2;
        const int b0  = (mb & 3) << 6;          // 64 batch rows per block
        const int c0  = c * C;
        const int t   = dir ? (T_ - 1 - (c0 + lt)) : (c0 + lt);

        const u16*   wih_d = wih + (size_t)dir * (768 * 128);
        const float* bih   = dir ? bih_b : bih_f;
        const float* bhh   = dir ? bhh_b : bhh_f;

        // w_ih fragments: wave wv owns gtiles wv*3 .. wv*3+2
        short8 wfrag[3][4];
#pragma unroll
        for (int j = 0; j < 3; j++) {
            int gt = wv * 3 + j;
            const u16* p = wih_d + (size_t)(gt * 16 + nl) * 128 + quad * 8;
#pragma unroll
            for (int kt = 0; kt < 4; kt++) wfrag[j][kt] = *(const short8*)(p + kt * 32);
        }

        // stage embedding tile (64 rows x 128 cols) as bf16: 2 iterations of 1024 threads
#pragma unroll
        for (int i = 0; i < 2; i++) {
            int idx = tid + i * 1024;
            int r = idx >> 5, cc = idx & 31;
            int tok = x[(b0 + r) * T_ + t];
            float4 v = *(const float4*)(emb + (size_t)tok * E_ + cc * 4);
            *(uint2*)&A[r][cc * 4] = pk4(v.x, v.y, v.z, v.w);
        }
        __syncthreads();

        f32x4 acc[3][4];
#pragma unroll
        for (int j = 0; j < 3; j++)
#pragma unroll
            for (int mi = 0; mi < 4; mi++) acc[j][mi] = (f32x4){0, 0, 0, 0};

#pragma unroll
        for (int kt = 0; kt < 4; kt++) {
            short8 a[4];
#pragma unroll
            for (int mi = 0; mi < 4; mi++)
                a[mi] = *(const short8*)&A[mi * 16 + nl][quad * 8 + kt * 32];
#pragma unroll
            for (int j = 0; j < 3; j++)
#pragma unroll
                for (int mi = 0; mi < 4; mi++)
                    acc[j][mi] = MFMA_BF16(wfrag[j][kt], a[mi], acc[j][mi]);  // w=A, emb=B
        }

        // epilogue: D[row=quad*4+rr = gate row in tile][col=nl = batch row]
        const int slot = (c & 1) * 2 * C + dir * C + lt;
#pragma unroll
        for (int j = 0; j < 3; j++) {
            int gt = wv * 3 + j;
            int gate = gt >> 4;
            const float4 bi = *(const float4*)(bih + gt * 16 + quad * 4);
            const float4 bh = *(const float4*)(bhh + gt * 16 + quad * 4);
            float bb[4];
            bb[0] = bi.x + (gate < 2 ? bh.x : 0.f);
            bb[1] = bi.y + (gate < 2 ? bh.y : 0.f);
            bb[2] = bi.z + (gate < 2 ? bh.z : 0.f);
            bb[3] = bi.w + (gate < 2 ? bh.w : 0.f);
#pragma unroll
            for (int mi = 0; mi < 4; mi++) {
                int btile = ((mb & 3) << 2) + mi;
                f32x4 v = acc[j][mi];
                size_t base = (((size_t)slot * 16 + btile) * 48 + gt) * 64 + lane;
                ((uint2*)xp)[base] = pk4(v[0] + bb[0], v[1] + bb[1], v[2] + bb[2], v[3] + bb[3]);
            }
        }
    }
}

// ---------------- FC head + row L2-normalize ----------------
__global__ void fc_head_kernel(const float* __restrict__ hstate,
                               const float* __restrict__ fc1w, const float* __restrict__ fc1b,
                               const float* __restrict__ fc2w, const float* __restrict__ fc2b,
                               float* __restrict__ out) {
    int row = blockIdx.x;
    int tid = threadIdx.x;  // 128
    __shared__ float hrow[512];
    __shared__ float hid[128];

    {
        int dir = tid >> 6, u = (tid & 63) * 4;
        float4 hv = *(const float4*)(hstate + ((size_t)(dir * 256 + row)) * 256 + u);
        *(float4*)(hrow + tid * 4) = hv;
    }
    __syncthreads();

    float acc = fc1b[tid];
    const float* wrow = fc1w + (size_t)tid * 512;
#pragma unroll 4
    for (int k = 0; k < 512; k += 4) {
        float4 w = *(const float4*)(wrow + k);
        acc += w.x * hrow[k] + w.y * hrow[k + 1] + w.z * hrow[k + 2] + w.w * hrow[k + 3];
    }
    hid[tid] = fmaxf(acc, 0.f);
    __syncthreads();

    if (tid < 64) {
        float a2 = fc2b[tid];
        const float* w2 = fc2w + (size_t)tid * 128;
#pragma unroll 4
        for (int k = 0; k < 128; k += 4) {
            float4 w = *(const float4*)(w2 + k);
            a2 += w.x * hid[k] + w.y * hid[k + 1] + w.z * hid[k + 2] + w.w * hid[k + 3];
        }
        float ss = a2 * a2;
#pragma unroll
        for (int off = 32; off > 0; off >>= 1) ss += __shfl_down(ss, off);
        ss = __shfl(ss, 0);
        float scale = 1.f / fmaxf(sqrtf(ss), 1e-12f);
        out[(size_t)row * 64 + tid] = a2 * scale;
    }
}

// ---------------- launcher ----------------
// ws: wih(393216) | whh(786432) | hstate(524288) | xp ring ((4C+1)*393216)
// C=16 minimum = 27.26 MB total; R4..R10 runs selected C=128
#define OFF_WIH  ((size_t)0)
#define OFF_WHH  ((size_t)393216)
#define OFF_HST  ((size_t)(393216 + 786432))
#define OFF_XP   ((size_t)(393216 + 786432 + 524288))
#define SLOT_B   ((size_t)393216)

extern "C" void kernel_launch(void* const* d_in, const int* in_sizes, int n_in,
                              void* d_out, int out_size, void* d_ws, size_t ws_size,
                              hipStream_t stream) {
    const int*   x      = (const int*)d_in[0];
    const int*   lens   = (const int*)d_in[1];
    const float* embedding = (const float*)d_in[2];
    const float* w_ih_f = (const float*)d_in[3];
    const float* w_hh_f = (const float*)d_in[4];
    const float* b_ih_f = (const float*)d_in[5];
    const float* b_hh_f = (const float*)d_in[6];
    const float* w_ih_b = (const float*)d_in[7];
    const float* w_hh_b = (const float*)d_in[8];
    const float* b_ih_b = (const float*)d_in[9];
    const float* b_hh_b = (const float*)d_in[10];
    const float* fc1_w  = (const float*)d_in[11];
    const float* fc1_b  = (const float*)d_in[12];
    const float* fc2_w  = (const float*)d_in[13];
    const float* fc2_b  = (const float*)d_in[14];
    float* out = (float*)d_out;

    char* ws = (char*)d_ws;
    u16*   wih_bf = (u16*)(ws + OFF_WIH);
    u16*   whh_bf = (u16*)(ws + OFF_WHH);
    float* hstate = (float*)(ws + OFF_HST);
    u16*   xp     = (u16*)(ws + OFF_XP);

    // largest chunk size whose 2-chunk ring fits the workspace (ws_size is constant
    // across calls, so this branch is graph-stable)
    int C = 16;
    if      (ws_size >= OFF_XP + (size_t)(4 * 128 + 1) * SLOT_B) C = 128;
    else if (ws_size >= OFF_XP + (size_t)(4 * 64  + 1) * SLOT_B) C = 64;
    else if (ws_size >= OFF_XP + (size_t)(4 * 32  + 1) * SLOT_B) C = 32;

    f32_to_bf16_kernel<<<192, 256, 0, stream>>>(w_ih_f, wih_bf, 49152);
    f32_to_bf16_kernel<<<192, 256, 0, stream>>>(w_ih_b, wih_bf + 98304, 49152);
    f32_to_bf16_kernel<<<384, 256, 0, stream>>>(w_hh_f, whh_bf, 98304);
    f32_to_bf16_kernel<<<384, 256, 0, stream>>>(w_hh_b, whh_bf + 196608, 98304);

    const int nchunks = T_ / C;
    const int grid = 32 + 8 * C;
    // launch c produces xp chunk c (if c<nchunks) and consumes chunk c-1 (if c>0)
    for (int c = 0; c <= nchunks; c++) {
        fused_chunk_kernel<<<grid, 1024, 0, stream>>>(x, embedding, wih_bf, whh_bf,
                                                      b_ih_f, b_hh_f, b_ih_b, b_hh_b,
                                                      lens, hstate, xp, C, c, nchunks);
    }

    fc_head_kernel<<<256, 128, 0, stream>>>(hstate, fc1_w, fc1_b, fc2_w, fc2_b, out);
}

// Round 12
// 870.963 us; speedup vs baseline: 1.4533x; 1.4533x over previous
//
#include <hip/hip_runtime.h>
#include <hip/hip_bf16.h>

#define B_ 256
#define T_ 512
#define E_ 128
#define H_ 256

typedef __attribute__((ext_vector_type(8))) short short8;
typedef __attribute__((ext_vector_type(4))) float f32x4;
typedef unsigned short u16;

#define MFMA_BF16(a, b, c) __builtin_amdgcn_mfma_f32_16x16x32_bf16((a), (b), (c), 0, 0, 0)

__device__ __forceinline__ u16 f2bf(float f) {
    union { float f; unsigned int u; } v; v.f = f;
    unsigned int u = v.u;
    unsigned int r = (u + 0x7fffu + ((u >> 16) & 1u)) >> 16;  // RNE
    return (u16)r;
}
__device__ __forceinline__ float bflo(unsigned int u) {
    union { unsigned int u; float f; } v; v.u = u << 16; return v.f;
}
__device__ __forceinline__ float bfhi(unsigned int u) {
    union { unsigned int u; float f; } v; v.u = u & 0xffff0000u; return v.f;
}
__device__ __forceinline__ f32x4 up2(uint2 p) {
    f32x4 r; r[0] = bflo(p.x); r[1] = bfhi(p.x); r[2] = bflo(p.y); r[3] = bfhi(p.y); return r;
}
// hardware packed f32->bf16 (RNE), 1 instr per 2 values (guide T12 recipe)
__device__ __forceinline__ uint2 pk4(float a, float b, float c, float d) {
    uint2 o;
    asm("v_cvt_pk_bf16_f32 %0, %1, %2" : "=v"(o.x) : "v"(a), "v"(b));
    asm("v_cvt_pk_bf16_f32 %0, %1, %2" : "=v"(o.y) : "v"(c), "v"(d));
    return o;
}
__device__ __forceinline__ float rcp_f(float x) { return __builtin_amdgcn_rcpf(x); }
__device__ __forceinline__ float sigm(float x) { return rcp_f(1.f + __expf(-x)); }

// ---------------- fp32 -> bf16 weight conversion ----------------
__global__ void f32_to_bf16_kernel(const float* __restrict__ src, u16* __restrict__ dst, int n2) {
    int i = blockIdx.x * blockDim.x + threadIdx.x;
    if (i < n2) {
        float2 v = ((const float2*)src)[i];
        ushort2 o; o.x = f2bf(v.x); o.y = f2bf(v.y);
        ((ushort2*)dst)[i] = o;
    }
}

// ---------------- fused chunk kernel: xp producer (chunk c) + GRU consumer (chunk c-1) ----------
// R11 post-mortem: VGPR_Count=64 (the 8-waves/SIMD budget) in R10 AND R11 -> compiler
// optimizes for phantom occupancy (LDS caps us at 4 waves/SIMD) and REMATERIALIZES weight
// loads from L2 every step: 16/wave/step in R10, 24 in R11 (the regression). R12 = R10
// structure (bn via LDS stage, proven 183us) + wr/wz fragments PINNED in registers via
// asm volatile("":"+v"(frag)) — the asm nominally modifies the value, so re-loading from
// memory is no longer a legal rematerialization; 64 weight VGPRs stay live. Budget:
// 64 pinned + ~48 working <= 128 regs/wave at 4 waves/SIMD (waves_per_eu(4,4)).
//
// xp layout (bf16, packed as uint2 per lane): ring slot = (chunkparity)*2C + dir*C + lt, then
//   [slot][btile16][gtile48][lane64]; gates r,z (gt<32) have b_ih+b_hh folded; n-gate b_ih only.
// Ring has 4C+1 slots; ls=C-1 prefetch reads stale/pad data that is always discarded (benign).
// Blocks 0..31 = GRU (scheduled first), blocks 32..32+8C-1 = xp producers.
// No intra-launch data dependency: gru reads ring parity (c-1)&1, xp writes parity c&1.
#define XP_SLOT_U2 49152   // 16*48*64 uint2 per t-slot

__attribute__((amdgpu_flat_work_group_size(1024, 1024), amdgpu_waves_per_eu(4, 4)))
__global__ void fused_chunk_kernel(const int* __restrict__ x, const float* __restrict__ emb,
                                   const u16* __restrict__ wih, const u16* __restrict__ whh,
                                   const float* __restrict__ bih_f, const float* __restrict__ bhh_f,
                                   const float* __restrict__ bih_b, const float* __restrict__ bhh_b,
                                   const int* __restrict__ lengths,
                                   float* __restrict__ hstate,   // [dir][256][256] f32
                                   u16* __restrict__ xp,
                                   int C, int c, int nchunks) {
    // LDS overlay: gru uses hfr + wn (144KB); xp producers use wn (as A[64][136], 17408B)
    __shared__ u16 hfr[2][4096];    // 16KB h mirrors, fragment-linear
    __shared__ u16 wn[65536];       // 128KB: n-gate weights, 16 sets x 8kt x 64lane x 8, frag-linear

    const int tid  = threadIdx.x;
    const int lane = tid & 63;
    const int nl   = lane & 15;
    const int quad = lane >> 4;
    const int wv   = tid >> 6;      // 0..15

    if (blockIdx.x < 32) {
        // ================= GRU consumer: chunk g = c-1 =================
        const int g = c - 1;
        if (g < 0) return;
        const int c0 = g * C;
        const int rg = g & 1;
        const int dir    = blockIdx.x >> 4;
        const int btile  = blockIdx.x & 15;
        const int b_base = btile << 4;

        __builtin_amdgcn_s_setprio(1);

        const u16*   whh_d = whh + (size_t)dir * (768 * 256);
        const float* bhh   = dir ? bhh_b : bhh_f;

        // stage all n-gate weight sets (rows 512..767), fragment-linear:
        // entry e=(su,kt,ln): row = 512 + su*16 + (ln&15), cols (ln>>4)*8 + kt*32
        for (int e = tid; e < 8192; e += 1024) {
            int su   = e >> 9;
            int kt_e = (e >> 6) & 7;
            int ln_e = e & 63;
            const u16* src = whh_d + (size_t)(512 + su * 16 + (ln_e & 15)) * 256
                           + (ln_e >> 4) * 8 + kt_e * 32;
            *(short8*)&wn[e * 8] = *(const short8*)src;
        }

        // r,z weight fragments: load ONCE, then pin in registers. The empty asm with "+v"
        // marks each fragment as modified -> re-loading from memory is no longer a legal
        // rematerialization, so all 64 weight VGPRs stay live across the step loop.
        const u16* pwr = whh_d + (size_t)(wv * 16 + nl) * 256 + quad * 8;
        const u16* pwz = whh_d + (size_t)(256 + wv * 16 + nl) * 256 + quad * 8;
        short8 wr[8], wz[8];
#pragma unroll
        for (int kt = 0; kt < 8; kt++) {
            wr[kt] = *(const short8*)(pwr + kt * 32);
            wz[kt] = *(const short8*)(pwz + kt * 32);
        }
#pragma unroll
        for (int kt = 0; kt < 8; kt++) {
            asm volatile("" : "+v"(wr[kt]));
            asm volatile("" : "+v"(wz[kt]));
        }

        const float4 bnh = *(const float4*)(bhh + 512 + wv * 16 + quad * 4);
        const int len = lengths[b_base + nl];

        // h master copy (fp32): hreg[rr] = h[batch nl][unit wv*16 + quad*4 + rr]
        float hreg[4];
        const int u0   = wv * 16 + quad * 4;
        const int widx = ((u0 >> 3) * 16 + nl) * 8 + (u0 & 7);
        float* hs = hstate + ((size_t)(dir * 256 + b_base + nl)) * 256 + u0;
        if (c0 == 0) {
#pragma unroll
            for (int rr = 0; rr < 4; rr++) hreg[rr] = 0.f;
        } else {
            float4 h4 = *(const float4*)hs;
            hreg[0] = h4.x; hreg[1] = h4.y; hreg[2] = h4.z; hreg[3] = h4.w;
        }
        *(uint2*)&hfr[0][widx] = pk4(hreg[0], hreg[1], hreg[2], hreg[3]);

        // xp pointers: wave wv's tiles are gt = gate*16 + wv
        const uint2* pgr;
        const uint2* pgz;
        const uint2* pgn;
        {
            size_t base = (((size_t)(rg * 2 * C + dir * C) * 16 + btile) * 48) * 64 + lane;
            pgr = (const uint2*)xp + base + (0 * 16 + wv) * 64;
            pgz = (const uint2*)xp + base + (1 * 16 + wv) * 64;
            pgn = (const uint2*)xp + base + (2 * 16 + wv) * 64;
        }
        uint2 pfr = pgr[0], pfz = pgz[0], pfn = pgn[0];

        __syncthreads();

        for (int ls = 0; ls < C; ls++) {
            const int s = c0 + ls;
            const int t = dir ? (T_ - 1 - s) : s;
            const int cur = ls & 1, nxt = cur ^ 1;

            f32x4 accr = up2(pfr);
            f32x4 accz = up2(pfz);
            f32x4 xpn  = up2(pfn);
            f32x4 accn = (f32x4){bnh.x, bnh.y, bnh.z, bnh.w};

            // prefetch next local step (ls=C-1 lands in stale/pad region; discarded)
            pgr += XP_SLOT_U2; pgz += XP_SLOT_U2; pgn += XP_SLOT_U2;
            pfr = pgr[0]; pfz = pgz[0]; pfn = pgn[0];

#pragma unroll
            for (int kt = 0; kt < 8; kt++) {
                short8 hv = *(const short8*)&hfr[cur][(kt * 64 + lane) * 8];
                accr = MFMA_BF16(wr[kt], hv, accr);
                accz = MFMA_BF16(wz[kt], hv, accz);
                short8 bn = *(const short8*)&wn[((wv * 8 + kt) * 64 + lane) * 8];
                accn = MFMA_BF16(bn, hv, accn);
            }

            const bool upd = (t < len);
#pragma unroll
            for (int rr = 0; rr < 4; rr++) {
                float r = sigm(accr[rr]);
                float z = sigm(accz[rr]);
                float npre = xpn[rr] + r * accn[rr];
                float nn = 1.f - 2.f * rcp_f(1.f + __expf(2.f * npre));
                float hn = nn + z * (hreg[rr] - nn);
                if (upd) hreg[rr] = hn;
            }
            *(uint2*)&hfr[nxt][widx] = pk4(hreg[0], hreg[1], hreg[2], hreg[3]);
            __syncthreads();
        }

        // carry h out
        *(float4*)hs = (float4){hreg[0], hreg[1], hreg[2], hreg[3]};
    } else {
        // ================= xp producer: chunk c (1024 threads: 3 gtiles/wave) =========
        if (c >= nchunks) return;
        u16 (*A)[136] = (u16 (*)[136])wn;

        const int mb0 = (int)blockIdx.x - 32;
        const int per_dir = C * 4;
        const int dir = (mb0 >= per_dir) ? 1 : 0;
        const int mb  = mb0 - dir * per_dir;
        const int lt  = mb >> 2;
        const int b0  = (mb & 3) << 6;          // 64 batch rows per block
        const int c0  = c * C;
        const int t   = dir ? (T_ - 1 - (c0 + lt)) : (c0 + lt);

        const u16*   wih_d = wih + (size_t)dir * (768 * 128);
        const float* bih   = dir ? bih_b : bih_f;
        const float* bhh   = dir ? bhh_b : bhh_f;

        // w_ih fragments: wave wv owns gtiles wv*3 .. wv*3+2
        short8 wfrag[3][4];
#pragma unroll
        for (int j = 0; j < 3; j++) {
            int gt = wv * 3 + j;
            const u16* p = wih_d + (size_t)(gt * 16 + nl) * 128 + quad * 8;
#pragma unroll
            for (int kt = 0; kt < 4; kt++) wfrag[j][kt] = *(const short8*)(p + kt * 32);
        }

        // stage embedding tile (64 rows x 128 cols) as bf16: 2 iterations of 1024 threads
#pragma unroll
        for (int i = 0; i < 2; i++) {
            int idx = tid + i * 1024;
            int r = idx >> 5, cc = idx & 31;
            int tok = x[(b0 + r) * T_ + t];
            float4 v = *(const float4*)(emb + (size_t)tok * E_ + cc * 4);
            *(uint2*)&A[r][cc * 4] = pk4(v.x, v.y, v.z, v.w);
        }
        __syncthreads();

        f32x4 acc[3][4];
#pragma unroll
        for (int j = 0; j < 3; j++)
#pragma unroll
            for (int mi = 0; mi < 4; mi++) acc[j][mi] = (f32x4){0, 0, 0, 0};

#pragma unroll
        for (int kt = 0; kt < 4; kt++) {
            short8 a[4];
#pragma unroll
            for (int mi = 0; mi < 4; mi++)
                a[mi] = *(const short8*)&A[mi * 16 + nl][quad * 8 + kt * 32];
#pragma unroll
            for (int j = 0; j < 3; j++)
#pragma unroll
                for (int mi = 0; mi < 4; mi++)
                    acc[j][mi] = MFMA_BF16(wfrag[j][kt], a[mi], acc[j][mi]);  // w=A, emb=B
        }

        // epilogue: D[row=quad*4+rr = gate row in tile][col=nl = batch row]
        const int slot = (c & 1) * 2 * C + dir * C + lt;
#pragma unroll
        for (int j = 0; j < 3; j++) {
            int gt = wv * 3 + j;
            int gate = gt >> 4;
            const float4 bi = *(const float4*)(bih + gt * 16 + quad * 4);
            const float4 bh = *(const float4*)(bhh + gt * 16 + quad * 4);
            float bb[4];
            bb[0] = bi.x + (gate < 2 ? bh.x : 0.f);
            bb[1] = bi.y + (gate < 2 ? bh.y : 0.f);
            bb[2] = bi.z + (gate < 2 ? bh.z : 0.f);
            bb[3] = bi.w + (gate < 2 ? bh.w : 0.f);
#pragma unroll
            for (int mi = 0; mi < 4; mi++) {
                int btile = ((mb & 3) << 2) + mi;
                f32x4 v = acc[j][mi];
                size_t base = (((size_t)slot * 16 + btile) * 48 + gt) * 64 + lane;
                ((uint2*)xp)[base] = pk4(v[0] + bb[0], v[1] + bb[1], v[2] + bb[2], v[3] + bb[3]);
            }
        }
    }
}

// ---------------- FC head + row L2-normalize ----------------
__global__ void fc_head_kernel(const float* __restrict__ hstate,
                               const float* __restrict__ fc1w, const float* __restrict__ fc1b,
                               const float* __restrict__ fc2w, const float* __restrict__ fc2b,
                               float* __restrict__ out) {
    int row = blockIdx.x;
    int tid = threadIdx.x;  // 128
    __shared__ float hrow[512];
    __shared__ float hid[128];

    {
        int dir = tid >> 6, u = (tid & 63) * 4;
        float4 hv = *(const float4*)(hstate + ((size_t)(dir * 256 + row)) * 256 + u);
        *(float4*)(hrow + tid * 4) = hv;
    }
    __syncthreads();

    float acc = fc1b[tid];
    const float* wrow = fc1w + (size_t)tid * 512;
#pragma unroll 4
    for (int k = 0; k < 512; k += 4) {
        float4 w = *(const float4*)(wrow + k);
        acc += w.x * hrow[k] + w.y * hrow[k + 1] + w.z * hrow[k + 2] + w.w * hrow[k + 3];
    }
    hid[tid] = fmaxf(acc, 0.f);
    __syncthreads();

    if (tid < 64) {
        float a2 = fc2b[tid];
        const float* w2 = fc2w + (size_t)tid * 128;
#pragma unroll 4
        for (int k = 0; k < 128; k += 4) {
            float4 w = *(const float4*)(w2 + k);
            a2 += w.x * hid[k] + w.y * hid[k + 1] + w.z * hid[k + 2] + w.w * hid[k + 3];
        }
        float ss = a2 * a2;
#pragma unroll
        for (int off = 32; off > 0; off >>= 1) ss += __shfl_down(ss, off);
        ss = __shfl(ss, 0);
        float scale = 1.f / fmaxf(sqrtf(ss), 1e-12f);
        out[(size_t)row * 64 + tid] = a2 * scale;
    }
}

// ---------------- launcher ----------------
// ws: wih(393216) | whh(786432) | hstate(524288) | xp ring ((4C+1)*393216)
// C=16 minimum = 27.26 MB total; R4..R11 runs selected C=128
#define OFF_WIH  ((size_t)0)
#define OFF_WHH  ((size_t)393216)
#define OFF_HST  ((size_t)(393216 + 786432))
#define OFF_XP   ((size_t)(393216 + 786432 + 524288))
#define SLOT_B   ((size_t)393216)

extern "C" void kernel_launch(void* const* d_in, const int* in_sizes, int n_in,
                              void* d_out, int out_size, void* d_ws, size_t ws_size,
                              hipStream_t stream) {
    const int*   x      = (const int*)d_in[0];
    const int*   lens   = (const int*)d_in[1];
    const float* embedding = (const float*)d_in[2];
    const float* w_ih_f = (const float*)d_in[3];
    const float* w_hh_f = (const float*)d_in[4];
    const float* b_ih_f = (const float*)d_in[5];
    const float* b_hh_f = (const float*)d_in[6];
    const float* w_ih_b = (const float*)d_in[7];
    const float* w_hh_b = (const float*)d_in[8];
    const float* b_ih_b = (const float*)d_in[9];
    const float* b_hh_b = (const float*)d_in[10];
    const float* fc1_w  = (const float*)d_in[11];
    const float* fc1_b  = (const float*)d_in[12];
    const float* fc2_w  = (const float*)d_in[13];
    const float* fc2_b  = (const float*)d_in[14];
    float* out = (float*)d_out;

    char* ws = (char*)d_ws;
    u16*   wih_bf = (u16*)(ws + OFF_WIH);
    u16*   whh_bf = (u16*)(ws + OFF_WHH);
    float* hstate = (float*)(ws + OFF_HST);
    u16*   xp     = (u16*)(ws + OFF_XP);

    // largest chunk size whose 2-chunk ring fits the workspace (ws_size is constant
    // across calls, so this branch is graph-stable)
    int C = 16;
    if      (ws_size >= OFF_XP + (size_t)(4 * 128 + 1) * SLOT_B) C = 128;
    else if (ws_size >= OFF_XP + (size_t)(4 * 64  + 1) * SLOT_B) C = 64;
    else if (ws_size >= OFF_XP + (size_t)(4 * 32  + 1) * SLOT_B) C = 32;

    f32_to_bf16_kernel<<<192, 256, 0, stream>>>(w_ih_f, wih_bf, 49152);
    f32_to_bf16_kernel<<<192, 256, 0, stream>>>(w_ih_b, wih_bf + 98304, 49152);
    f32_to_bf16_kernel<<<384, 256, 0, stream>>>(w_hh_f, whh_bf, 98304);
    f32_to_bf16_kernel<<<384, 256, 0, stream>>>(w_hh_b, whh_bf + 196608, 98304);

    const int nchunks = T_ / C;
    const int grid = 32 + 8 * C;
    // launch c produces xp chunk c (if c<nchunks) and consumes chunk c-1 (if c>0)
    for (int c = 0; c <= nchunks; c++) {
        fused_chunk_kernel<<<grid, 1024, 0, stream>>>(x, embedding, wih_bf, whh_bf,
                                                      b_ih_f, b_hh_f, b_ih_b, b_hh_b,
                                                      lens, hstate, xp, C, c, nchunks);
    }

    fc_head_kernel<<<256, 128, 0, stream>>>(hstate, fc1_w, fc1_b, fc2_w, fc2_b, out);
}